// Round 2
// baseline (511.451 us; speedup 1.0000x reference)
//
#include <hip/hip_runtime.h>
#include <hip/hip_fp16.h>
#include <cstdint>
#include <cstddef>

#define HID 2560
#define NH  32
#define DHD 80
#define DHP 96
#define NB  2
#define NS  2048
#define NL  512

typedef _Float16 half8_t __attribute__((ext_vector_type(8)));
typedef float f32x4_t __attribute__((ext_vector_type(4)));

__device__ __forceinline__ void gload_lds16(const __half* g, __half* l) {
  __builtin_amdgcn_global_load_lds(
      (const __attribute__((address_space(1))) unsigned int*)g,
      (__attribute__((address_space(3))) unsigned int*)l, 16, 0, 0);
}

// ---------------- cast fp32 -> fp16, vectorized x4 ----------------
__global__ __launch_bounds__(256) void cast_f2h(const float* __restrict__ in,
                                                __half* __restrict__ out, int n4) {
  int i = blockIdx.x * 256 + threadIdx.x;
  if (i >= n4) return;
  float4 v = ((const float4*)in)[i];
  union { __half h[4]; uint2 u; } r;
  r.h[0] = __float2half(v.x);
  r.h[1] = __float2half(v.y);
  r.h[2] = __float2half(v.z);
  r.h[3] = __float2half(v.w);
  ((uint2*)out)[i] = r.u;
}

// ---------------- zero only the pad columns (d=80..95) of Q and K --------
// (replaces rocclr fillBuffer memsets which ran at 35 GB/s / 180 us each)
__global__ __launch_bounds__(256) void zero_pads(__half* __restrict__ Qa,
                                                 __half* __restrict__ Ka) {
  const int qrows = NB * NH * NS;
  const int krows = NB * NH * NL;
  int i = blockIdx.x * 256 + threadIdx.x;
  const uint4 z = {0, 0, 0, 0};
  if (i < qrows) {
    uint4* p = (uint4*)(Qa + (size_t)i * DHP + DHD);  // byte off = i*192+160, 16B aligned
    p[0] = z; p[1] = z;
  } else if (i < qrows + krows) {
    uint4* p = (uint4*)(Ka + (size_t)(i - qrows) * DHP + DHD);
    p[0] = z; p[1] = z;
  }
}

// ---------------- GEMM: C = A[M,K] x Bt[N,K]^T, fp16 in, fp32 acc --------
// 128x128 tile, BK=32, 256 threads (4 waves, 2x2), m97-style structure.
// MODE 0: write Q -> [B,H,S,DHP] fp16, folded softmax scale
// MODE 1: write K -> [B,H,L,DHP] fp16
// MODE 2: write V -> [B,H,DHP,L] fp16 (transposed for PV B^T-pattern)
// MODE 3: write out = gate * acc, fp32 [M,HID]
template<int MODE>
__global__ __launch_bounds__(256) void gemm_bt(const __half* __restrict__ A,
                                               const __half* __restrict__ Bt,
                                               void* __restrict__ Cout,
                                               int M, int N, int K,
                                               const float* __restrict__ gate_p) {
  __shared__ __half As[128 * 32];
  __shared__ __half Bs[128 * 32];
  const int tid  = threadIdx.x;
  const int lane = tid & 63;
  const int wave = tid >> 6;
  const int wr = wave >> 1, wc = wave & 1;
  const int fr = lane & 15, kb = lane >> 4;
  const int bm = blockIdx.y, bn = blockIdx.x;

  // staging: thread t covers LDS bytes [t*16, t*16+16) (+4096 for 2nd issue)
  const int sr = tid >> 2;            // row 0..63
  const int sc = (tid & 3) * 8;       // half-offset within BK=32
  const __half* gA = A  + (size_t)(bm * 128 + sr) * K + sc;
  const __half* gB = Bt + (size_t)(bn * 128 + sr) * K + sc;
  __half* lA = As + tid * 8;
  __half* lB = Bs + tid * 8;

  f32x4_t acc[4][4] = {};

  const int nk = K >> 5;
  for (int kt = 0; kt < nk; ++kt) {
    const __half* ga = gA + (size_t)kt * 32;
    const __half* gb = gB + (size_t)kt * 32;
    gload_lds16(ga, lA);
    gload_lds16(ga + (size_t)64 * K, lA + 2048);
    gload_lds16(gb, lB);
    gload_lds16(gb + (size_t)64 * K, lB + 2048);
    __syncthreads();
    half8_t af[4], bf[4];
#pragma unroll
    for (int m = 0; m < 4; ++m)
      af[m] = *(const half8_t*)(As + (wr * 64 + m * 16 + fr) * 32 + kb * 8);
#pragma unroll
    for (int n = 0; n < 4; ++n)
      bf[n] = *(const half8_t*)(Bs + (wc * 64 + n * 16 + fr) * 32 + kb * 8);
#pragma unroll
    for (int m = 0; m < 4; ++m)
#pragma unroll
      for (int n = 0; n < 4; ++n)
        acc[m][n] = __builtin_amdgcn_mfma_f32_16x16x32_f16(af[m], bf[n], acc[m][n], 0, 0, 0);
    __syncthreads();
  }

  float gate = 0.f;
  if (MODE == 3) gate = tanhf(gate_p[0]);

#pragma unroll
  for (int m = 0; m < 4; ++m) {
#pragma unroll
    for (int n = 0; n < 4; ++n) {
#pragma unroll
      for (int r = 0; r < 4; ++r) {
        const int row = bm * 128 + wr * 64 + m * 16 + kb * 4 + r;
        const int col = bn * 128 + wc * 64 + n * 16 + fr;
        const float v = acc[m][n][r];
        if (MODE == 0) {
          const int b = row >> 11, s = row & 2047;
          const int h = col / DHD, d = col - h * DHD;
          ((__half*)Cout)[(((size_t)(b * NH + h)) * NS + s) * DHP + d] =
              __float2half(v * 0.11180339887498949f);  // 1/sqrt(80) folded into Q
        } else if (MODE == 1) {
          const int b = row >> 9, l = row & 511;
          const int h = col / DHD, d = col - h * DHD;
          ((__half*)Cout)[(((size_t)(b * NH + h)) * NL + l) * DHP + d] = __float2half(v);
        } else if (MODE == 2) {
          const int b = row >> 9, l = row & 511;
          const int h = col / DHD, d = col - h * DHD;
          ((__half*)Cout)[(((size_t)(b * NH + h)) * DHP + d) * NL + l] = __float2half(v);
        } else {
          ((float*)Cout)[(size_t)row * HID + col] = gate * v;
        }
      }
    }
  }
}

// ---------------- attention: scores -> exact softmax -> P out + PV -------
// grid (NS/64, NB*NH); 4 waves x 16 Q-rows each. L=512 scores per row in
// registers (32 f32x4/lane). Softmax reduced across 16-lane col groups.
__global__ __launch_bounds__(256) void attn_kernel(const __half* __restrict__ Q,
                                                   const __half* __restrict__ Kt,
                                                   const __half* __restrict__ Vt,
                                                   float* __restrict__ P,
                                                   __half* __restrict__ AO) {
  // per-wave P tile 16x512 fp16, row stride 520 halfs (1040 B: 16B-aligned,
  // 2-way bank aliasing only = free)
  __shared__ __half Pl[4 * 16 * 520];
  const int tid = threadIdx.x;
  const int lane = tid & 63, wave = tid >> 6;
  const int fr = lane & 15, kb = lane >> 4;
  const int bh = blockIdx.y;
  const int r0 = blockIdx.x * 64 + wave * 16;

  const __half* Qb = Q  + ((size_t)bh * NS + r0) * DHP;
  const __half* Kb = Kt + (size_t)bh * NL * DHP;
  const __half* Vb = Vt + (size_t)bh * DHP * NL;

  // Q A-fragments (rows r0..r0+15, K = 96 padded, pad zeros)
  half8_t aq[3];
#pragma unroll
  for (int kk = 0; kk < 3; ++kk)
    aq[kk] = *(const half8_t*)(Qb + (size_t)fr * DHP + kk * 32 + kb * 8);

  // scores: 32 col-tiles of 16
  f32x4_t scr[32];
#pragma unroll
  for (int nt = 0; nt < 32; ++nt) {
    f32x4_t a = {};
#pragma unroll
    for (int kk = 0; kk < 3; ++kk) {
      half8_t bf = *(const half8_t*)(Kb + (size_t)(nt * 16 + fr) * DHP + kk * 32 + kb * 8);
      a = __builtin_amdgcn_mfma_f32_16x16x32_f16(aq[kk], bf, a, 0, 0, 0);
    }
    scr[nt] = a;
  }

  // softmax: lane holds rows kb*4+r (r=0..3), col nt*16+fr
  __half* Plw = Pl + wave * (16 * 520);
#pragma unroll
  for (int r = 0; r < 4; ++r) {
    float m = -1e30f;
#pragma unroll
    for (int nt = 0; nt < 32; ++nt) m = fmaxf(m, scr[nt][r]);
#pragma unroll
    for (int d = 1; d < 16; d <<= 1) m = fmaxf(m, __shfl_xor(m, d));
    float s = 0.f;
#pragma unroll
    for (int nt = 0; nt < 32; ++nt) {
      float p = __expf(scr[nt][r] - m);
      scr[nt][r] = p;
      s += p;
    }
#pragma unroll
    for (int d = 1; d < 16; d <<= 1) s += __shfl_xor(s, d);
    const float iv = 1.f / s;
    const int srow = r0 + kb * 4 + r;
    float* Pr = P + ((size_t)bh * NS + srow) * NL;
#pragma unroll
    for (int nt = 0; nt < 32; ++nt) {
      float p = scr[nt][r] * iv;
      Pr[nt * 16 + fr] = p;                                  // exact attn_weights
      Plw[(kb * 4 + r) * 520 + nt * 16 + fr] = __float2half(p);
    }
  }
  __syncthreads();

  // PV: out[16 x 80], A = P from LDS, B = V^T frags from global (L2-resident)
  f32x4_t oc[5] = {};
#pragma unroll
  for (int k0 = 0; k0 < 16; ++k0) {
    half8_t ap = *(const half8_t*)(Plw + fr * 520 + k0 * 32 + kb * 8);
#pragma unroll
    for (int n = 0; n < 5; ++n) {
      half8_t bv = *(const half8_t*)(Vb + (size_t)(n * 16 + fr) * NL + k0 * 32 + kb * 8);
      oc[n] = __builtin_amdgcn_mfma_f32_16x16x32_f16(ap, bv, oc[n], 0, 0, 0);
    }
  }

  const int b = bh >> 5, h = bh & 31;
#pragma unroll
  for (int n = 0; n < 5; ++n)
#pragma unroll
    for (int r = 0; r < 4; ++r) {
      const int srow = r0 + kb * 4 + r;
      AO[((size_t)b * NS + srow) * HID + h * DHD + n * 16 + fr] = __float2half(oc[n][r]);
    }
}

extern "C" void kernel_launch(void* const* d_in, const int* in_sizes, int n_in,
                              void* d_out, int out_size, void* d_ws, size_t ws_size,
                              hipStream_t stream) {
  const float* X  = (const float*)d_in[0];
  const float* LS = (const float*)d_in[1];
  const float* Wq = (const float*)d_in[2];
  const float* Wk = (const float*)d_in[3];
  const float* Wv = (const float*)d_in[4];
  const float* Wo = (const float*)d_in[5];
  const float* gp = (const float*)d_in[6];
  float* out  = (float*)d_out;
  float* Pout = out + (size_t)NB * NS * HID;  // attn_weights, output index 1

  char* w = (char*)d_ws;
  auto alloc = [&](size_t bytes) {
    char* p = w;
    w += (bytes + 255) & ~(size_t)255;
    return p;
  };
  __half* Xh  = (__half*)alloc((size_t)NB * NS * HID * 2);
  __half* Lh  = (__half*)alloc((size_t)NB * NL * HID * 2);
  __half* Wqh = (__half*)alloc((size_t)HID * HID * 2);
  __half* Wkh = (__half*)alloc((size_t)HID * HID * 2);
  __half* Wvh = (__half*)alloc((size_t)HID * HID * 2);
  __half* Woh = (__half*)alloc((size_t)HID * HID * 2);
  __half* Qa  = (__half*)alloc((size_t)NB * NH * NS * DHP * 2);
  __half* Ka  = (__half*)alloc((size_t)NB * NH * NL * DHP * 2);
  __half* Va  = (__half*)alloc((size_t)NB * NH * DHP * NL * 2);
  __half* AOh = Xh;  // alias: Xh is dead after the Q projection

  auto cast = [&](const float* src, __half* dst, size_t n) {
    int n4 = (int)(n / 4);
    cast_f2h<<<dim3((n4 + 255) / 256), dim3(256), 0, stream>>>(src, dst, n4);
  };
  cast(X,  Xh,  (size_t)NB * NS * HID);
  cast(LS, Lh,  (size_t)NB * NL * HID);
  cast(Wq, Wqh, (size_t)HID * HID);
  cast(Wk, Wkh, (size_t)HID * HID);
  cast(Wv, Wvh, (size_t)HID * HID);
  cast(Wo, Woh, (size_t)HID * HID);

  // zero only the DHP pad columns of Q/K (they enter the K=96 MFMA loop)
  {
    const int rows = NB * NH * NS + NB * NH * NL;
    zero_pads<<<dim3((rows + 255) / 256), dim3(256), 0, stream>>>(Qa, Ka);
  }

  gemm_bt<0><<<dim3(HID / 128, NB * NS / 128), dim3(256), 0, stream>>>(
      Xh, Wqh, Qa, NB * NS, HID, HID, nullptr);
  gemm_bt<1><<<dim3(HID / 128, NB * NL / 128), dim3(256), 0, stream>>>(
      Lh, Wkh, Ka, NB * NL, HID, HID, nullptr);
  gemm_bt<2><<<dim3(HID / 128, NB * NL / 128), dim3(256), 0, stream>>>(
      Lh, Wvh, Va, NB * NL, HID, HID, nullptr);
  attn_kernel<<<dim3(NS / 64, NB * NH), dim3(256), 0, stream>>>(
      Qa, Ka, Va, Pout, AOh);
  gemm_bt<3><<<dim3(HID / 128, NB * NS / 128), dim3(256), 0, stream>>>(
      AOh, Woh, out, NB * NS, HID, HID, gp);
}

// Round 3
// 479.783 us; speedup vs baseline: 1.0660x; 1.0660x over previous
//
#include <hip/hip_runtime.h>
#include <hip/hip_fp16.h>
#include <cstdint>
#include <cstddef>

#define HID 2560
#define NH  32
#define DHD 80
#define DHP 96
#define NB  2
#define NS  2048
#define NL  512

typedef _Float16 half8_t __attribute__((ext_vector_type(8)));
typedef float f32x4_t __attribute__((ext_vector_type(4)));

__device__ __forceinline__ void gload_lds16(const __half* g, __half* l) {
  __builtin_amdgcn_global_load_lds(
      (const __attribute__((address_space(1))) unsigned int*)g,
      (__attribute__((address_space(3))) unsigned int*)l, 16, 0, 0);
}

// ---------------- cast fp32 -> fp16, vectorized x4 ----------------
__global__ __launch_bounds__(256) void cast_f2h(const float* __restrict__ in,
                                                __half* __restrict__ out, int n4) {
  int i = blockIdx.x * 256 + threadIdx.x;
  if (i >= n4) return;
  float4 v = ((const float4*)in)[i];
  union { __half h[4]; uint2 u; } r;
  r.h[0] = __float2half(v.x);
  r.h[1] = __float2half(v.y);
  r.h[2] = __float2half(v.z);
  r.h[3] = __float2half(v.w);
  ((uint2*)out)[i] = r.u;
}

// ---------------- zero only the pad columns (d=80..95) of Q and K --------
__global__ __launch_bounds__(256) void zero_pads(__half* __restrict__ Qa,
                                                 __half* __restrict__ Ka) {
  const int qrows = NB * NH * NS;
  const int krows = NB * NH * NL;
  int i = blockIdx.x * 256 + threadIdx.x;
  const uint4 z = {0, 0, 0, 0};
  if (i < qrows) {
    uint4* p = (uint4*)(Qa + (size_t)i * DHP + DHD);
    p[0] = z; p[1] = z;
  } else if (i < qrows + krows) {
    uint4* p = (uint4*)(Ka + (size_t)(i - qrows) * DHP + DHD);
    p[0] = z; p[1] = z;
  }
}

// ============ 256x256 tile, BK=64, 8-wave, counted-vmcnt GEMM ============
// C = A[M,K] x Bt[N,K]^T. 512 thr = 8 waves (2M x 4N), per-wave 128x64 out.
// LDS: 2 banks x (A 32KB + B 32KB) = 128 KB. XOR swizzle byte^=(row&7)<<4
// applied via pre-swizzled global source (linear LDS dest for gload_lds) +
// swizzled ds_read address.  Two raw s_barriers per K-step; vmcnt(2) keeps
// next-tile loads in flight across barriers (T3/T4), setprio around MFMA (T5).
// MODE 0: Q -> [B,H,S,DHP] fp16 with softmax scale folded.
// MODE 3: out = gate * acc, fp32 [M,HID].
template<int MODE>
__global__ __launch_bounds__(512) void gemm256(const __half* __restrict__ A,
                                               const __half* __restrict__ Bt,
                                               void* __restrict__ Cout,
                                               int M, int N, int K,
                                               const float* __restrict__ gate_p) {
  __shared__ __half smem[2][32768];  // [bank][A: 0..16383 | B: 16384..32767]
  const int tid  = threadIdx.x;
  const int lane = tid & 63;
  const int wave = tid >> 6;
  const int wr = wave >> 2, wc = wave & 3;   // 2 x 4 wave grid
  const int fr = lane & 15, kb = lane >> 4;

  // XCD-aware bijective swizzle (grid % 8 == 0 for our shapes)
  int wg = blockIdx.x;
  const int nwg = gridDim.x;
  if ((nwg & 7) == 0) wg = (wg & 7) * (nwg >> 3) + (wg >> 3);
  const int nbn = N >> 8;
  const int bm = wg / nbn, bn = wg - bm * nbn;

  // staging: thread t covers LDS bytes [t*16,+16) of an 8KB chunk (linear),
  // so its GLOBAL col-chunk is pre-swizzled: j_g = (t&7) ^ (row&7)
  const int sr = tid >> 3;                 // row within 64-row chunk
  const int sj = (tid & 7) ^ (sr & 7);     // swizzled 16B col chunk
  const __half* gA = A  + (size_t)(bm * 256 + sr) * K + sj * 8;
  const __half* gB = Bt + (size_t)(bn * 256 + sr) * K + sj * 8;

  // stage half-tile h (0:A rows0-127, 1:A rows128-255, 2:B0-127, 3:B128-255)
  auto stage = [&](int h, int kt, int bank) {
    const __half* gbase = (h < 2) ? gA : gB;
    const int rbase = (h & 1) * 128;
#pragma unroll
    for (int i = 0; i < 2; ++i) {
      const __half* g = gbase + (size_t)(rbase + i * 64) * K + (size_t)kt * 64;
      __half* l = &smem[bank][(h < 2 ? 0 : 16384) + (rbase + i * 64) * 64 + tid * 8];
      gload_lds16(g, l);
    }
  };

  // swizzled fragment reads (16B aligned; row&7 == fr&7 at all uses)
  auto rdA = [&](int m, int kk, int bank) -> half8_t {
    const int row = wr * 128 + m * 16 + fr;
    const int off = row * 128 + ((kk * 64 + kb * 16) ^ ((fr & 7) << 4));
    return *(const half8_t*)((const char*)(&smem[bank][0]) + off);
  };
  auto rdB = [&](int n, int kk, int bank) -> half8_t {
    const int row = wc * 64 + n * 16 + fr;
    const int off = row * 128 + ((kk * 64 + kb * 16) ^ ((fr & 7) << 4));
    return *(const half8_t*)((const char*)(&smem[bank][16384]) + off);
  };

  f32x4_t acc[8][4] = {};
  half8_t af[4][2], bf[4][2];

  // prologue: stage all 4 half-tiles of kt=0 into bank 0 (8 loads in flight)
#pragma unroll
  for (int h = 0; h < 4; ++h) stage(h, 0, 0);

  const int nk = K >> 6;
  for (int kt = 0; kt < nk; ++kt) {
    const int bk = kt & 1, nb = bk ^ 1;
    const bool pf = (kt + 1 < nk);

    // ---- phase 0: quadrant (m0-3, n0-1); reads 8A + 4B
    if (pf) stage(0, kt + 1, nb);
    if (pf) asm volatile("s_waitcnt vmcnt(2)" ::: "memory");
    else    asm volatile("s_waitcnt vmcnt(0)" ::: "memory");
    asm volatile("s_barrier" ::: "memory");   // bank bk fully landed, all waves
#pragma unroll
    for (int m = 0; m < 4; ++m)
#pragma unroll
      for (int kk = 0; kk < 2; ++kk) af[m][kk] = rdA(m, kk, bk);
#pragma unroll
    for (int n = 0; n < 2; ++n)
#pragma unroll
      for (int kk = 0; kk < 2; ++kk) bf[n][kk] = rdB(n, kk, bk);
    __builtin_amdgcn_s_setprio(1);
#pragma unroll
    for (int m = 0; m < 4; ++m)
#pragma unroll
      for (int n = 0; n < 2; ++n)
#pragma unroll
        for (int kk = 0; kk < 2; ++kk)
          acc[m][n] = __builtin_amdgcn_mfma_f32_16x16x32_f16(af[m][kk], bf[n][kk], acc[m][n], 0, 0, 0);
    __builtin_amdgcn_s_setprio(0);

    // ---- phase 1: (m0-3, n2-3); reads 4B, reuses af
    if (pf) stage(1, kt + 1, nb);
#pragma unroll
    for (int n = 2; n < 4; ++n)
#pragma unroll
      for (int kk = 0; kk < 2; ++kk) bf[n][kk] = rdB(n, kk, bk);
    __builtin_amdgcn_s_setprio(1);
#pragma unroll
    for (int m = 0; m < 4; ++m)
#pragma unroll
      for (int n = 2; n < 4; ++n)
#pragma unroll
        for (int kk = 0; kk < 2; ++kk)
          acc[m][n] = __builtin_amdgcn_mfma_f32_16x16x32_f16(af[m][kk], bf[n][kk], acc[m][n], 0, 0, 0);
    __builtin_amdgcn_s_setprio(0);

    // ---- phase 2: (m4-7, n2-3); reads 8A, reuses bf[2..3]
    if (pf) stage(2, kt + 1, nb);
#pragma unroll
    for (int m = 0; m < 4; ++m)
#pragma unroll
      for (int kk = 0; kk < 2; ++kk) af[m][kk] = rdA(m + 4, kk, bk);
    __builtin_amdgcn_s_setprio(1);
#pragma unroll
    for (int m = 0; m < 4; ++m)
#pragma unroll
      for (int n = 2; n < 4; ++n)
#pragma unroll
        for (int kk = 0; kk < 2; ++kk)
          acc[m + 4][n] = __builtin_amdgcn_mfma_f32_16x16x32_f16(af[m][kk], bf[n][kk], acc[m + 4][n], 0, 0, 0);
    __builtin_amdgcn_s_setprio(0);

    // ---- phase 3: (m4-7, n0-1); no reads, reuses af + bf[0..1]
    if (pf) stage(3, kt + 1, nb);
    __builtin_amdgcn_s_setprio(1);
#pragma unroll
    for (int m = 0; m < 4; ++m)
#pragma unroll
      for (int n = 0; n < 2; ++n)
#pragma unroll
        for (int kk = 0; kk < 2; ++kk)
          acc[m + 4][n] = __builtin_amdgcn_mfma_f32_16x16x32_f16(af[m][kk], bf[n][kk], acc[m + 4][n], 0, 0, 0);
    __builtin_amdgcn_s_setprio(0);

    asm volatile("s_barrier" ::: "memory");   // all reads of bank bk done
  }

  float gate = 0.f;
  if (MODE == 3) gate = tanhf(gate_p[0]);

#pragma unroll
  for (int m = 0; m < 8; ++m)
#pragma unroll
    for (int n = 0; n < 4; ++n)
#pragma unroll
      for (int r = 0; r < 4; ++r) {
        const int row = bm * 256 + wr * 128 + m * 16 + kb * 4 + r;
        const int col = bn * 256 + wc * 64 + n * 16 + fr;
        const float v = acc[m][n][r];
        if (MODE == 0) {
          const int b = row >> 11, s = row & 2047;
          const int h = col / DHD, d = col - h * DHD;
          ((__half*)Cout)[(((size_t)(b * NH + h)) * NS + s) * DHP + d] =
              __float2half(v * 0.11180339887498949f);
        } else {
          ((float*)Cout)[(size_t)row * HID + col] = gate * v;
        }
      }
}

// ---------------- 128x128 GEMM (kept for K/V proj: small grids) ----------
// MODE 1: K -> [B,H,L,DHP] fp16; MODE 2: V -> [B,H,DHP,L] fp16 (transposed)
template<int MODE>
__global__ __launch_bounds__(256) void gemm_bt(const __half* __restrict__ A,
                                               const __half* __restrict__ Bt,
                                               void* __restrict__ Cout,
                                               int M, int N, int K,
                                               const float* __restrict__ gate_p) {
  __shared__ __half As[128 * 32];
  __shared__ __half Bs[128 * 32];
  const int tid  = threadIdx.x;
  const int lane = tid & 63;
  const int wave = tid >> 6;
  const int wr = wave >> 1, wc = wave & 1;
  const int fr = lane & 15, kb = lane >> 4;
  const int bm = blockIdx.y, bn = blockIdx.x;

  const int sr = tid >> 2;
  const int sc = (tid & 3) * 8;
  const __half* gA = A  + (size_t)(bm * 128 + sr) * K + sc;
  const __half* gB = Bt + (size_t)(bn * 128 + sr) * K + sc;
  __half* lA = As + tid * 8;
  __half* lB = Bs + tid * 8;

  f32x4_t acc[4][4] = {};

  const int nk = K >> 5;
  for (int kt = 0; kt < nk; ++kt) {
    const __half* ga = gA + (size_t)kt * 32;
    const __half* gb = gB + (size_t)kt * 32;
    gload_lds16(ga, lA);
    gload_lds16(ga + (size_t)64 * K, lA + 2048);
    gload_lds16(gb, lB);
    gload_lds16(gb + (size_t)64 * K, lB + 2048);
    __syncthreads();
    half8_t af[4], bf[4];
#pragma unroll
    for (int m = 0; m < 4; ++m)
      af[m] = *(const half8_t*)(As + (wr * 64 + m * 16 + fr) * 32 + kb * 8);
#pragma unroll
    for (int n = 0; n < 4; ++n)
      bf[n] = *(const half8_t*)(Bs + (wc * 64 + n * 16 + fr) * 32 + kb * 8);
#pragma unroll
    for (int m = 0; m < 4; ++m)
#pragma unroll
      for (int n = 0; n < 4; ++n)
        acc[m][n] = __builtin_amdgcn_mfma_f32_16x16x32_f16(af[m], bf[n], acc[m][n], 0, 0, 0);
    __syncthreads();
  }

#pragma unroll
  for (int m = 0; m < 4; ++m) {
#pragma unroll
    for (int n = 0; n < 4; ++n) {
#pragma unroll
      for (int r = 0; r < 4; ++r) {
        const int row = bm * 128 + wr * 64 + m * 16 + kb * 4 + r;
        const int col = bn * 128 + wc * 64 + n * 16 + fr;
        const float v = acc[m][n][r];
        if (MODE == 1) {
          const int b = row >> 9, l = row & 511;
          const int h = col / DHD, d = col - h * DHD;
          ((__half*)Cout)[(((size_t)(b * NH + h)) * NL + l) * DHP + d] = __float2half(v);
        } else {
          const int b = row >> 9, l = row & 511;
          const int h = col / DHD, d = col - h * DHD;
          ((__half*)Cout)[(((size_t)(b * NH + h)) * DHP + d) * NL + l] = __float2half(v);
        }
      }
    }
  }
}

// ---------------- attention: scores -> exact softmax -> P out + PV -------
__global__ __launch_bounds__(256) void attn_kernel(const __half* __restrict__ Q,
                                                   const __half* __restrict__ Kt,
                                                   const __half* __restrict__ Vt,
                                                   float* __restrict__ P,
                                                   __half* __restrict__ AO) {
  __shared__ __half Pl[4 * 16 * 520];
  const int tid = threadIdx.x;
  const int lane = tid & 63, wave = tid >> 6;
  const int fr = lane & 15, kb = lane >> 4;
  const int bh = blockIdx.y;
  const int r0 = blockIdx.x * 64 + wave * 16;

  const __half* Qb = Q  + ((size_t)bh * NS + r0) * DHP;
  const __half* Kb = Kt + (size_t)bh * NL * DHP;
  const __half* Vb = Vt + (size_t)bh * DHP * NL;

  half8_t aq[3];
#pragma unroll
  for (int kk = 0; kk < 3; ++kk)
    aq[kk] = *(const half8_t*)(Qb + (size_t)fr * DHP + kk * 32 + kb * 8);

  f32x4_t scr[32];
#pragma unroll
  for (int nt = 0; nt < 32; ++nt) {
    f32x4_t a = {};
#pragma unroll
    for (int kk = 0; kk < 3; ++kk) {
      half8_t bfv = *(const half8_t*)(Kb + (size_t)(nt * 16 + fr) * DHP + kk * 32 + kb * 8);
      a = __builtin_amdgcn_mfma_f32_16x16x32_f16(aq[kk], bfv, a, 0, 0, 0);
    }
    scr[nt] = a;
  }

  __half* Plw = Pl + wave * (16 * 520);
#pragma unroll
  for (int r = 0; r < 4; ++r) {
    float m = -1e30f;
#pragma unroll
    for (int nt = 0; nt < 32; ++nt) m = fmaxf(m, scr[nt][r]);
#pragma unroll
    for (int d = 1; d < 16; d <<= 1) m = fmaxf(m, __shfl_xor(m, d));
    float s = 0.f;
#pragma unroll
    for (int nt = 0; nt < 32; ++nt) {
      float p = __expf(scr[nt][r] - m);
      scr[nt][r] = p;
      s += p;
    }
#pragma unroll
    for (int d = 1; d < 16; d <<= 1) s += __shfl_xor(s, d);
    const float iv = 1.f / s;
    const int srow = r0 + kb * 4 + r;
    float* Pr = P + ((size_t)bh * NS + srow) * NL;
#pragma unroll
    for (int nt = 0; nt < 32; ++nt) {
      float p = scr[nt][r] * iv;
      Pr[nt * 16 + fr] = p;
      Plw[(kb * 4 + r) * 520 + nt * 16 + fr] = __float2half(p);
    }
  }
  __syncthreads();

  f32x4_t oc[5] = {};
#pragma unroll
  for (int k0 = 0; k0 < 16; ++k0) {
    half8_t ap = *(const half8_t*)(Plw + fr * 520 + k0 * 32 + kb * 8);
#pragma unroll
    for (int n = 0; n < 5; ++n) {
      half8_t bv = *(const half8_t*)(Vb + (size_t)(n * 16 + fr) * NL + k0 * 32 + kb * 8);
      oc[n] = __builtin_amdgcn_mfma_f32_16x16x32_f16(ap, bv, oc[n], 0, 0, 0);
    }
  }

  const int b = bh >> 5, h = bh & 31;
#pragma unroll
  for (int n = 0; n < 5; ++n)
#pragma unroll
    for (int r = 0; r < 4; ++r) {
      const int srow = r0 + kb * 4 + r;
      AO[((size_t)b * NS + srow) * HID + h * DHD + n * 16 + fr] = __float2half(oc[n][r]);
    }
}

extern "C" void kernel_launch(void* const* d_in, const int* in_sizes, int n_in,
                              void* d_out, int out_size, void* d_ws, size_t ws_size,
                              hipStream_t stream) {
  const float* X  = (const float*)d_in[0];
  const float* LS = (const float*)d_in[1];
  const float* Wq = (const float*)d_in[2];
  const float* Wk = (const float*)d_in[3];
  const float* Wv = (const float*)d_in[4];
  const float* Wo = (const float*)d_in[5];
  const float* gp = (const float*)d_in[6];
  float* out  = (float*)d_out;
  float* Pout = out + (size_t)NB * NS * HID;

  char* w = (char*)d_ws;
  auto alloc = [&](size_t bytes) {
    char* p = w;
    w += (bytes + 255) & ~(size_t)255;
    return p;
  };
  __half* Xh  = (__half*)alloc((size_t)NB * NS * HID * 2);
  __half* Lh  = (__half*)alloc((size_t)NB * NL * HID * 2);
  __half* Wqh = (__half*)alloc((size_t)HID * HID * 2);
  __half* Wkh = (__half*)alloc((size_t)HID * HID * 2);
  __half* Wvh = (__half*)alloc((size_t)HID * HID * 2);
  __half* Woh = (__half*)alloc((size_t)HID * HID * 2);
  __half* Qa  = (__half*)alloc((size_t)NB * NH * NS * DHP * 2);
  __half* Ka  = (__half*)alloc((size_t)NB * NH * NL * DHP * 2);
  __half* Va  = (__half*)alloc((size_t)NB * NH * DHP * NL * 2);
  __half* AOh = Xh;  // Xh dead after Q projection

  auto cast = [&](const float* src, __half* dst, size_t n) {
    int n4 = (int)(n / 4);
    cast_f2h<<<dim3((n4 + 255) / 256), dim3(256), 0, stream>>>(src, dst, n4);
  };
  cast(X,  Xh,  (size_t)NB * NS * HID);
  cast(LS, Lh,  (size_t)NB * NL * HID);
  cast(Wq, Wqh, (size_t)HID * HID);
  cast(Wk, Wkh, (size_t)HID * HID);
  cast(Wv, Wvh, (size_t)HID * HID);
  cast(Wo, Woh, (size_t)HID * HID);

  {
    const int rows = NB * NH * NS + NB * NH * NL;
    zero_pads<<<dim3((rows + 255) / 256), dim3(256), 0, stream>>>(Qa, Ka);
  }

  // Q-proj / O-proj: 256^2 counted-vmcnt kernel (160 blocks each)
  gemm256<0><<<dim3((NB * NS / 256) * (HID / 256)), dim3(512), 0, stream>>>(
      Xh, Wqh, Qa, NB * NS, HID, HID, nullptr);
  gemm_bt<1><<<dim3(HID / 128, NB * NL / 128), dim3(256), 0, stream>>>(
      Lh, Wkh, Ka, NB * NL, HID, HID, nullptr);
  gemm_bt<2><<<dim3(HID / 128, NB * NL / 128), dim3(256), 0, stream>>>(
      Lh, Wvh, Va, NB * NL, HID, HID, nullptr);
  attn_kernel<<<dim3(NS / 64, NB * NH), dim3(256), 0, stream>>>(
      Qa, Ka, Va, Pout, AOh);
  gemm256<3><<<dim3((NB * NS / 256) * (HID / 256)), dim3(512), 0, stream>>>(
      AOh, Woh, out, NB * NS, HID, HID, gp);
}

// Round 4
// 394.937 us; speedup vs baseline: 1.2950x; 1.2148x over previous
//
#include <hip/hip_runtime.h>
#include <hip/hip_fp16.h>
#include <cstdint>
#include <cstddef>

#define HID 2560
#define NH  32
#define DHD 80
#define DHP 96
#define NB  2
#define NS  2048
#define NL  512

typedef _Float16 half8_t __attribute__((ext_vector_type(8)));
typedef float f32x4_t __attribute__((ext_vector_type(4)));

__device__ __forceinline__ void gload_lds16(const __half* g, __half* l) {
  __builtin_amdgcn_global_load_lds(
      (const __attribute__((address_space(1))) unsigned int*)g,
      (__attribute__((address_space(3))) unsigned int*)l, 16, 0, 0);
}

// ---------------- cast fp32 -> fp16, vectorized x4 ----------------
__global__ __launch_bounds__(256) void cast_f2h(const float* __restrict__ in,
                                                __half* __restrict__ out, int n4) {
  int i = blockIdx.x * 256 + threadIdx.x;
  if (i >= n4) return;
  float4 v = ((const float4*)in)[i];
  union { __half h[4]; uint2 u; } r;
  r.h[0] = __float2half(v.x);
  r.h[1] = __float2half(v.y);
  r.h[2] = __float2half(v.z);
  r.h[3] = __float2half(v.w);
  ((uint2*)out)[i] = r.u;
}

// ---------------- zero only the pad columns (d=80..95) of Q and K --------
__global__ __launch_bounds__(256) void zero_pads(__half* __restrict__ Qa,
                                                 __half* __restrict__ Ka) {
  const int qrows = NB * NH * NS;
  const int krows = NB * NH * NL;
  int i = blockIdx.x * 256 + threadIdx.x;
  const uint4 z = {0, 0, 0, 0};
  if (i < qrows) {
    uint4* p = (uint4*)(Qa + (size_t)i * DHP + DHD);
    p[0] = z; p[1] = z;
  } else if (i < qrows + krows) {
    uint4* p = (uint4*)(Ka + (size_t)(i - qrows) * DHP + DHD);
    p[0] = z; p[1] = z;
  }
}

// ============ 256x256-tile, BK=64, 8-wave core (T2+T3+T4+T5) =============
// C-tile = A[bm*256.., :] x Bt[bn*256.., :]^T, K = HID.  512 thr, 8 waves
// (2M x 4N), per-wave 128x64 out. LDS 2 banks x 64KB. XOR swizzle
// byte^=(row&7)<<4 via pre-swizzled global source + swizzled ds_read.
// 4 phases per K-step, each {ds_reads || stage -> barrier -> MFMA -> barrier};
// counted vmcnt(2) once per K-step (never 0 mid-loop).
__device__ __forceinline__ void gemm256_core(const __half* A, const __half* Bt,
                                             int bm, int bn, __half* smem,
                                             f32x4_t (&acc)[8][4]) {
  const int K = HID;
  const int tid  = threadIdx.x;
  const int lane = tid & 63;
  const int wave = tid >> 6;
  const int wr = wave >> 2, wc = wave & 3;
  const int fr = lane & 15, kb = lane >> 4;

  const int sr = tid >> 3;                 // staging row within 64-row chunk
  const int sj = (tid & 7) ^ (sr & 7);     // pre-swizzled 16B col chunk
  const __half* gA = A  + (size_t)(bm * 256 + sr) * K + sj * 8;
  const __half* gB = Bt + (size_t)(bn * 256 + sr) * K + sj * 8;

  auto stage = [&](int h, int kt, int bank) {
    const __half* gbase = (h < 2) ? gA : gB;
    const int rbase = (h & 1) * 128;
#pragma unroll
    for (int i = 0; i < 2; ++i) {
      const __half* g = gbase + (size_t)(rbase + i * 64) * K + (size_t)kt * 64;
      __half* l = smem + bank * 32768 + (h < 2 ? 0 : 16384) + (rbase + i * 64) * 64 + tid * 8;
      gload_lds16(g, l);
    }
  };
  auto rdA = [&](int m, int kk, int bank) -> half8_t {
    const int row = wr * 128 + m * 16 + fr;
    const int off = row * 128 + ((kk * 64 + kb * 16) ^ ((fr & 7) << 4));
    return *(const half8_t*)((const char*)(smem + bank * 32768) + off);
  };
  auto rdB = [&](int n, int kk, int bank) -> half8_t {
    const int row = wc * 64 + n * 16 + fr;
    const int off = row * 128 + ((kk * 64 + kb * 16) ^ ((fr & 7) << 4));
    return *(const half8_t*)((const char*)(smem + bank * 32768 + 16384) + off);
  };

  half8_t af[4][2], bf[4][2];

  // prologue: stage all 4 half-tiles of kt=0 into bank 0 (8 loads in flight)
#pragma unroll
  for (int h = 0; h < 4; ++h) stage(h, 0, 0);

  const int nk = K >> 6;
  for (int kt = 0; kt < nk; ++kt) {
    const int bk = kt & 1, nb2 = bk ^ 1;
    const bool pf = (kt + 1 < nk);

    // ---- phase 0: (m0-3, n0-1); 8A + 4B reads (after bank-ready barrier)
    if (pf) stage(0, kt + 1, nb2);
    if (pf) asm volatile("s_waitcnt vmcnt(2)" ::: "memory");
    else    asm volatile("s_waitcnt vmcnt(0)" ::: "memory");
    asm volatile("s_barrier" ::: "memory");
#pragma unroll
    for (int m = 0; m < 4; ++m)
#pragma unroll
      for (int kk = 0; kk < 2; ++kk) af[m][kk] = rdA(m, kk, bk);
#pragma unroll
    for (int n = 0; n < 2; ++n)
#pragma unroll
      for (int kk = 0; kk < 2; ++kk) bf[n][kk] = rdB(n, kk, bk);
    __builtin_amdgcn_s_setprio(1);
#pragma unroll
    for (int m = 0; m < 4; ++m)
#pragma unroll
      for (int n = 0; n < 2; ++n)
#pragma unroll
        for (int kk = 0; kk < 2; ++kk)
          acc[m][n] = __builtin_amdgcn_mfma_f32_16x16x32_f16(af[m][kk], bf[n][kk], acc[m][n], 0, 0, 0);
    __builtin_amdgcn_s_setprio(0);
    asm volatile("s_barrier" ::: "memory");

    // ---- phase 1: (m0-3, n2-3); 4B reads, reuse af
#pragma unroll
    for (int n = 2; n < 4; ++n)
#pragma unroll
      for (int kk = 0; kk < 2; ++kk) bf[n][kk] = rdB(n, kk, bk);
    if (pf) stage(1, kt + 1, nb2);
    asm volatile("s_barrier" ::: "memory");
    __builtin_amdgcn_s_setprio(1);
#pragma unroll
    for (int m = 0; m < 4; ++m)
#pragma unroll
      for (int n = 2; n < 4; ++n)
#pragma unroll
        for (int kk = 0; kk < 2; ++kk)
          acc[m][n] = __builtin_amdgcn_mfma_f32_16x16x32_f16(af[m][kk], bf[n][kk], acc[m][n], 0, 0, 0);
    __builtin_amdgcn_s_setprio(0);
    asm volatile("s_barrier" ::: "memory");

    // ---- phase 2: (m4-7, n2-3); 8A reads, reuse bf[2..3]
#pragma unroll
    for (int m = 0; m < 4; ++m)
#pragma unroll
      for (int kk = 0; kk < 2; ++kk) af[m][kk] = rdA(m + 4, kk, bk);
    if (pf) stage(2, kt + 1, nb2);
    asm volatile("s_barrier" ::: "memory");
    __builtin_amdgcn_s_setprio(1);
#pragma unroll
    for (int m = 0; m < 4; ++m)
#pragma unroll
      for (int n = 2; n < 4; ++n)
#pragma unroll
        for (int kk = 0; kk < 2; ++kk)
          acc[m + 4][n] = __builtin_amdgcn_mfma_f32_16x16x32_f16(af[m][kk], bf[n][kk], acc[m + 4][n], 0, 0, 0);
    __builtin_amdgcn_s_setprio(0);
    asm volatile("s_barrier" ::: "memory");

    // ---- phase 3: (m4-7, n0-1); no reads, reuse af + bf[0..1]
    if (pf) stage(3, kt + 1, nb2);
    asm volatile("s_barrier" ::: "memory");
    __builtin_amdgcn_s_setprio(1);
#pragma unroll
    for (int m = 0; m < 4; ++m)
#pragma unroll
      for (int n = 0; n < 2; ++n)
#pragma unroll
        for (int kk = 0; kk < 2; ++kk)
          acc[m + 4][n] = __builtin_amdgcn_mfma_f32_16x16x32_f16(af[m][kk], bf[n][kk], acc[m + 4][n], 0, 0, 0);
    __builtin_amdgcn_s_setprio(0);
    asm volatile("s_barrier" ::: "memory");   // all reads of bank bk done
  }
}

// -------- fused QKV projection: 240 blocks = 160 Q + 40 K + 40 V ---------
__global__ __launch_bounds__(512) void fused_qkv(const __half* __restrict__ X,
                                                 const __half* __restrict__ L,
                                                 const __half* __restrict__ Wq,
                                                 const __half* __restrict__ Wk,
                                                 const __half* __restrict__ Wv,
                                                 __half* __restrict__ Qa,
                                                 __half* __restrict__ Ka,
                                                 __half* __restrict__ Va) {
  __shared__ __half smem[2 * 32768];
  int wg = blockIdx.x;                       // 240 = 8 XCD * 30
  wg = (wg & 7) * 30 + (wg >> 3);            // bijective XCD swizzle

  int mode, bm, bn;
  const __half *A, *B;
  if (wg < 160)      { mode = 0; A = X; B = Wq; bm = wg / 10;        bn = wg - bm * 10; }
  else if (wg < 200) { mode = 1; A = L; B = Wk; bm = (wg - 160) / 10; bn = (wg - 160) - bm * 10; }
  else               { mode = 2; A = L; B = Wv; bm = (wg - 200) / 10; bn = (wg - 200) - bm * 10; }

  f32x4_t acc[8][4] = {};
  gemm256_core(A, B, bm, bn, smem, acc);

  const int lane = threadIdx.x & 63, wave = threadIdx.x >> 6;
  const int wr = wave >> 2, wc = wave & 3;
  const int fr = lane & 15, kb = lane >> 4;

#pragma unroll
  for (int m = 0; m < 8; ++m)
#pragma unroll
    for (int n = 0; n < 4; ++n)
#pragma unroll
      for (int r = 0; r < 4; ++r) {
        const int row = bm * 256 + wr * 128 + m * 16 + kb * 4 + r;
        const int col = bn * 256 + wc * 64 + n * 16 + fr;
        const float v = acc[m][n][r];
        const int h = col / DHD, d = col - h * DHD;
        if (mode == 0) {
          const int b = row >> 11, s = row & 2047;
          Qa[(((size_t)(b * NH + h)) * NS + s) * DHP + d] =
              __float2half(v * 0.11180339887498949f);     // 1/sqrt(80) folded
        } else if (mode == 1) {
          const int b = row >> 9, l = row & 511;
          Ka[(((size_t)(b * NH + h)) * NL + l) * DHP + d] = __float2half(v);
        } else {
          const int b = row >> 9, l = row & 511;
          Va[(((size_t)(b * NH + h)) * DHP + d) * NL + l] = __float2half(v);
        }
      }
}

// -------- O projection: out = gate * (AO x Wo^T), fp32, 160 blocks -------
__global__ __launch_bounds__(512) void gemm256_o(const __half* __restrict__ A,
                                                 const __half* __restrict__ Bt,
                                                 float* __restrict__ out,
                                                 const float* __restrict__ gate_p) {
  __shared__ __half smem[2 * 32768];
  int wg = blockIdx.x;                       // 160 = 8 XCD * 20
  wg = (wg & 7) * 20 + (wg >> 3);
  const int bm = wg / 10, bn = wg - bm * 10;

  f32x4_t acc[8][4] = {};
  gemm256_core(A, Bt, bm, bn, smem, acc);

  const float gate = tanhf(gate_p[0]);
  const int lane = threadIdx.x & 63, wave = threadIdx.x >> 6;
  const int wr = wave >> 2, wc = wave & 3;
  const int fr = lane & 15, kb = lane >> 4;

#pragma unroll
  for (int m = 0; m < 8; ++m)
#pragma unroll
    for (int n = 0; n < 4; ++n)
#pragma unroll
      for (int r = 0; r < 4; ++r) {
        const int row = bm * 256 + wr * 128 + m * 16 + kb * 4 + r;
        const int col = bn * 256 + wc * 64 + n * 16 + fr;
        out[(size_t)row * HID + col] = gate * acc[m][n][r];
      }
}

// ---------------- attention: scores -> exact softmax -> P out + PV -------
__global__ __launch_bounds__(256) void attn_kernel(const __half* __restrict__ Q,
                                                   const __half* __restrict__ Kt,
                                                   const __half* __restrict__ Vt,
                                                   float* __restrict__ P,
                                                   __half* __restrict__ AO) {
  __shared__ __half Pl[4 * 16 * 520];
  const int tid = threadIdx.x;
  const int lane = tid & 63, wave = tid >> 6;
  const int fr = lane & 15, kb = lane >> 4;
  const int bh = blockIdx.y;
  const int r0 = blockIdx.x * 64 + wave * 16;

  const __half* Qb = Q  + ((size_t)bh * NS + r0) * DHP;
  const __half* Kb = Kt + (size_t)bh * NL * DHP;
  const __half* Vb = Vt + (size_t)bh * DHP * NL;

  half8_t aq[3];
#pragma unroll
  for (int kk = 0; kk < 3; ++kk)
    aq[kk] = *(const half8_t*)(Qb + (size_t)fr * DHP + kk * 32 + kb * 8);

  f32x4_t scr[32];
#pragma unroll
  for (int nt = 0; nt < 32; ++nt) {
    f32x4_t a = {};
#pragma unroll
    for (int kk = 0; kk < 3; ++kk) {
      half8_t bfv = *(const half8_t*)(Kb + (size_t)(nt * 16 + fr) * DHP + kk * 32 + kb * 8);
      a = __builtin_amdgcn_mfma_f32_16x16x32_f16(aq[kk], bfv, a, 0, 0, 0);
    }
    scr[nt] = a;
  }

  __half* Plw = Pl + wave * (16 * 520);
#pragma unroll
  for (int r = 0; r < 4; ++r) {
    float m = -1e30f;
#pragma unroll
    for (int nt = 0; nt < 32; ++nt) m = fmaxf(m, scr[nt][r]);
#pragma unroll
    for (int d = 1; d < 16; d <<= 1) m = fmaxf(m, __shfl_xor(m, d));
    float s = 0.f;
#pragma unroll
    for (int nt = 0; nt < 32; ++nt) {
      float p = __expf(scr[nt][r] - m);
      scr[nt][r] = p;
      s += p;
    }
#pragma unroll
    for (int d = 1; d < 16; d <<= 1) s += __shfl_xor(s, d);
    const float iv = 1.f / s;
    const int srow = r0 + kb * 4 + r;
    float* Pr = P + ((size_t)bh * NS + srow) * NL;
#pragma unroll
    for (int nt = 0; nt < 32; ++nt) {
      float p = scr[nt][r] * iv;
      Pr[nt * 16 + fr] = p;
      Plw[(kb * 4 + r) * 520 + nt * 16 + fr] = __float2half(p);
    }
  }
  __syncthreads();

  f32x4_t oc[5] = {};
#pragma unroll
  for (int k0 = 0; k0 < 16; ++k0) {
    half8_t ap = *(const half8_t*)(Plw + fr * 520 + k0 * 32 + kb * 8);
#pragma unroll
    for (int n = 0; n < 5; ++n) {
      half8_t bv = *(const half8_t*)(Vb + (size_t)(n * 16 + fr) * NL + k0 * 32 + kb * 8);
      oc[n] = __builtin_amdgcn_mfma_f32_16x16x32_f16(ap, bv, oc[n], 0, 0, 0);
    }
  }

  const int b = bh >> 5, h = bh & 31;
#pragma unroll
  for (int n = 0; n < 5; ++n)
#pragma unroll
    for (int r = 0; r < 4; ++r) {
      const int srow = r0 + kb * 4 + r;
      AO[((size_t)b * NS + srow) * HID + h * DHD + n * 16 + fr] = __float2half(oc[n][r]);
    }
}

extern "C" void kernel_launch(void* const* d_in, const int* in_sizes, int n_in,
                              void* d_out, int out_size, void* d_ws, size_t ws_size,
                              hipStream_t stream) {
  const float* X  = (const float*)d_in[0];
  const float* LS = (const float*)d_in[1];
  const float* Wq = (const float*)d_in[2];
  const float* Wk = (const float*)d_in[3];
  const float* Wv = (const float*)d_in[4];
  const float* Wo = (const float*)d_in[5];
  const float* gp = (const float*)d_in[6];
  float* out  = (float*)d_out;
  float* Pout = out + (size_t)NB * NS * HID;

  char* w = (char*)d_ws;
  auto alloc = [&](size_t bytes) {
    char* p = w;
    w += (bytes + 255) & ~(size_t)255;
    return p;
  };
  __half* Xh  = (__half*)alloc((size_t)NB * NS * HID * 2);
  __half* Lh  = (__half*)alloc((size_t)NB * NL * HID * 2);
  __half* Wqh = (__half*)alloc((size_t)HID * HID * 2);
  __half* Wkh = (__half*)alloc((size_t)HID * HID * 2);
  __half* Wvh = (__half*)alloc((size_t)HID * HID * 2);
  __half* Woh = (__half*)alloc((size_t)HID * HID * 2);
  __half* Qa  = (__half*)alloc((size_t)NB * NH * NS * DHP * 2);
  __half* Ka  = (__half*)alloc((size_t)NB * NH * NL * DHP * 2);
  __half* Va  = (__half*)alloc((size_t)NB * NH * DHP * NL * 2);
  __half* AOh = Xh;  // Xh dead after QKV projection

  auto cast = [&](const float* src, __half* dst, size_t n) {
    int n4 = (int)(n / 4);
    cast_f2h<<<dim3((n4 + 255) / 256), dim3(256), 0, stream>>>(src, dst, n4);
  };
  cast(X,  Xh,  (size_t)NB * NS * HID);
  cast(LS, Lh,  (size_t)NB * NL * HID);
  cast(Wq, Wqh, (size_t)HID * HID);
  cast(Wk, Wkh, (size_t)HID * HID);
  cast(Wv, Wvh, (size_t)HID * HID);
  cast(Wo, Woh, (size_t)HID * HID);

  {
    const int rows = NB * NH * NS + NB * NH * NL;
    zero_pads<<<dim3((rows + 255) / 256), dim3(256), 0, stream>>>(Qa, Ka);
  }

  fused_qkv<<<dim3(240), dim3(512), 0, stream>>>(Xh, Lh, Wqh, Wkh, Wvh, Qa, Ka, Va);
  attn_kernel<<<dim3(NS / 64, NB * NH), dim3(256), 0, stream>>>(
      Qa, Ka, Va, Pout, AOh);
  gemm256_o<<<dim3(160), dim3(512), 0, stream>>>(AOh, Woh, out, gp);
}

// Round 5
// 332.830 us; speedup vs baseline: 1.5367x; 1.1866x over previous
//
#include <hip/hip_runtime.h>
#include <hip/hip_fp16.h>
#include <cstdint>
#include <cstddef>

#define HID 2560
#define NH  32
#define DHD 80
#define DHP 96
#define NB  2
#define NS  2048
#define NL  512

typedef _Float16 half8_t __attribute__((ext_vector_type(8)));
typedef float f32x4_t __attribute__((ext_vector_type(4)));

__device__ __forceinline__ void gload_lds16(const __half* g, __half* l) {
  __builtin_amdgcn_global_load_lds(
      (const __attribute__((address_space(1))) unsigned int*)g,
      (__attribute__((address_space(3))) unsigned int*)l, 16, 0, 0);
}

// ------------- single fused cast fp32 -> fp16 (all 6 tensors) ------------
__global__ __launch_bounds__(256) void cast_all(const float* __restrict__ X,
                                                const float* __restrict__ LS,
                                                const float* __restrict__ Wq,
                                                const float* __restrict__ Wk,
                                                const float* __restrict__ Wv,
                                                const float* __restrict__ Wo,
                                                __half* __restrict__ Xh,
                                                __half* __restrict__ Lh,
                                                __half* __restrict__ Wqh,
                                                __half* __restrict__ Wkh,
                                                __half* __restrict__ Wvh,
                                                __half* __restrict__ Woh) {
  const int nX = NB * NS * HID / 4, nL = NB * NL * HID / 4, nW = HID * HID / 4;
  const int total = nX + nL + 4 * nW;
  for (int i = blockIdx.x * 256 + threadIdx.x; i < total; i += gridDim.x * 256) {
    const float* src; __half* dst; int off;
    if (i < nX) { src = X; dst = Xh; off = i; }
    else if (i < nX + nL) { src = LS; dst = Lh; off = i - nX; }
    else {
      int j = i - nX - nL;
      int w = j / nW; off = j - w * nW;
      src = (w == 0) ? Wq : (w == 1) ? Wk : (w == 2) ? Wv : Wo;
      dst = (w == 0) ? Wqh : (w == 1) ? Wkh : (w == 2) ? Wvh : Woh;
    }
    float4 v = ((const float4*)src)[off];
    union { __half h[4]; uint2 u; } r;
    r.h[0] = __float2half(v.x);
    r.h[1] = __float2half(v.y);
    r.h[2] = __float2half(v.z);
    r.h[3] = __float2half(v.w);
    ((uint2*)dst)[off] = r.u;
  }
}

// ---------------- zero only the pad columns (d=80..95) of Q and K --------
__global__ __launch_bounds__(256) void zero_pads(__half* __restrict__ Qa,
                                                 __half* __restrict__ Ka) {
  const int qrows = NB * NH * NS;
  const int krows = NB * NH * NL;
  int i = blockIdx.x * 256 + threadIdx.x;
  const uint4 z = {0, 0, 0, 0};
  if (i < qrows) {
    uint4* p = (uint4*)(Qa + (size_t)i * DHP + DHD);
    p[0] = z; p[1] = z;
  } else if (i < qrows + krows) {
    uint4* p = (uint4*)(Ka + (size_t)(i - qrows) * DHP + DHD);
    p[0] = z; p[1] = z;
  }
}

// ============ 256x256-tile, BK=64, 8-wave core (T2+T3+T4+T5) =============
__device__ __forceinline__ void gemm256_core(const __half* A, const __half* Bt,
                                             int bm, int bn, __half* smem,
                                             f32x4_t (&acc)[8][4]) {
  const int K = HID;
  const int tid  = threadIdx.x;
  const int lane = tid & 63;
  const int wave = tid >> 6;
  const int wr = wave >> 2, wc = wave & 3;
  const int fr = lane & 15, kb = lane >> 4;

  const int sr = tid >> 3;
  const int sj = (tid & 7) ^ (sr & 7);
  const __half* gA = A  + (size_t)(bm * 256 + sr) * K + sj * 8;
  const __half* gB = Bt + (size_t)(bn * 256 + sr) * K + sj * 8;

  auto stage = [&](int h, int kt, int bank) {
    const __half* gbase = (h < 2) ? gA : gB;
    const int rbase = (h & 1) * 128;
#pragma unroll
    for (int i = 0; i < 2; ++i) {
      const __half* g = gbase + (size_t)(rbase + i * 64) * K + (size_t)kt * 64;
      __half* l = smem + bank * 32768 + (h < 2 ? 0 : 16384) + (rbase + i * 64) * 64 + tid * 8;
      gload_lds16(g, l);
    }
  };
  auto rdA = [&](int m, int kk, int bank) -> half8_t {
    const int row = wr * 128 + m * 16 + fr;
    const int off = row * 128 + ((kk * 64 + kb * 16) ^ ((fr & 7) << 4));
    return *(const half8_t*)((const char*)(smem + bank * 32768) + off);
  };
  auto rdB = [&](int n, int kk, int bank) -> half8_t {
    const int row = wc * 64 + n * 16 + fr;
    const int off = row * 128 + ((kk * 64 + kb * 16) ^ ((fr & 7) << 4));
    return *(const half8_t*)((const char*)(smem + bank * 32768 + 16384) + off);
  };

  half8_t af[4][2], bf[4][2];

#pragma unroll
  for (int h = 0; h < 4; ++h) stage(h, 0, 0);

  const int nk = K >> 6;
  for (int kt = 0; kt < nk; ++kt) {
    const int bk = kt & 1, nb2 = bk ^ 1;
    const bool pf = (kt + 1 < nk);

    if (pf) stage(0, kt + 1, nb2);
    if (pf) asm volatile("s_waitcnt vmcnt(2)" ::: "memory");
    else    asm volatile("s_waitcnt vmcnt(0)" ::: "memory");
    asm volatile("s_barrier" ::: "memory");
#pragma unroll
    for (int m = 0; m < 4; ++m)
#pragma unroll
      for (int kk = 0; kk < 2; ++kk) af[m][kk] = rdA(m, kk, bk);
#pragma unroll
    for (int n = 0; n < 2; ++n)
#pragma unroll
      for (int kk = 0; kk < 2; ++kk) bf[n][kk] = rdB(n, kk, bk);
    __builtin_amdgcn_s_setprio(1);
#pragma unroll
    for (int m = 0; m < 4; ++m)
#pragma unroll
      for (int n = 0; n < 2; ++n)
#pragma unroll
        for (int kk = 0; kk < 2; ++kk)
          acc[m][n] = __builtin_amdgcn_mfma_f32_16x16x32_f16(af[m][kk], bf[n][kk], acc[m][n], 0, 0, 0);
    __builtin_amdgcn_s_setprio(0);
    asm volatile("s_barrier" ::: "memory");

#pragma unroll
    for (int n = 2; n < 4; ++n)
#pragma unroll
      for (int kk = 0; kk < 2; ++kk) bf[n][kk] = rdB(n, kk, bk);
    if (pf) stage(1, kt + 1, nb2);
    asm volatile("s_barrier" ::: "memory");
    __builtin_amdgcn_s_setprio(1);
#pragma unroll
    for (int m = 0; m < 4; ++m)
#pragma unroll
      for (int n = 2; n < 4; ++n)
#pragma unroll
        for (int kk = 0; kk < 2; ++kk)
          acc[m][n] = __builtin_amdgcn_mfma_f32_16x16x32_f16(af[m][kk], bf[n][kk], acc[m][n], 0, 0, 0);
    __builtin_amdgcn_s_setprio(0);
    asm volatile("s_barrier" ::: "memory");

#pragma unroll
    for (int m = 0; m < 4; ++m)
#pragma unroll
      for (int kk = 0; kk < 2; ++kk) af[m][kk] = rdA(m + 4, kk, bk);
    if (pf) stage(2, kt + 1, nb2);
    asm volatile("s_barrier" ::: "memory");
    __builtin_amdgcn_s_setprio(1);
#pragma unroll
    for (int m = 0; m < 4; ++m)
#pragma unroll
      for (int n = 2; n < 4; ++n)
#pragma unroll
        for (int kk = 0; kk < 2; ++kk)
          acc[m + 4][n] = __builtin_amdgcn_mfma_f32_16x16x32_f16(af[m][kk], bf[n][kk], acc[m + 4][n], 0, 0, 0);
    __builtin_amdgcn_s_setprio(0);
    asm volatile("s_barrier" ::: "memory");

    if (pf) stage(3, kt + 1, nb2);
    asm volatile("s_barrier" ::: "memory");
    __builtin_amdgcn_s_setprio(1);
#pragma unroll
    for (int m = 0; m < 4; ++m)
#pragma unroll
      for (int n = 0; n < 2; ++n)
#pragma unroll
        for (int kk = 0; kk < 2; ++kk)
          acc[m + 4][n] = __builtin_amdgcn_mfma_f32_16x16x32_f16(af[m][kk], bf[n][kk], acc[m + 4][n], 0, 0, 0);
    __builtin_amdgcn_s_setprio(0);
    asm volatile("s_barrier" ::: "memory");
  }
}

// -------- fused QKV projection: 240 blocks = 160 Q + 40 K + 40 V ---------
__global__ __launch_bounds__(512) void fused_qkv(const __half* __restrict__ X,
                                                 const __half* __restrict__ L,
                                                 const __half* __restrict__ Wq,
                                                 const __half* __restrict__ Wk,
                                                 const __half* __restrict__ Wv,
                                                 __half* __restrict__ Qa,
                                                 __half* __restrict__ Ka,
                                                 __half* __restrict__ Va) {
  __shared__ __half smem[2 * 32768];
  int wg = blockIdx.x;                       // 240 = 8 XCD * 30
  wg = (wg & 7) * 30 + (wg >> 3);            // bijective XCD swizzle

  int mode, bm, bn;
  const __half *A, *B;
  if (wg < 160)      { mode = 0; A = X; B = Wq; bm = wg / 10;        bn = wg - bm * 10; }
  else if (wg < 200) { mode = 1; A = L; B = Wk; bm = (wg - 160) / 10; bn = (wg - 160) - bm * 10; }
  else               { mode = 2; A = L; B = Wv; bm = (wg - 200) / 10; bn = (wg - 200) - bm * 10; }

  f32x4_t acc[8][4] = {};
  gemm256_core(A, B, bm, bn, smem, acc);

  const int lane = threadIdx.x & 63, wave = threadIdx.x >> 6;
  const int wr = wave >> 2, wc = wave & 3;
  const int fr = lane & 15, kb = lane >> 4;

#pragma unroll
  for (int m = 0; m < 8; ++m)
#pragma unroll
    for (int n = 0; n < 4; ++n)
#pragma unroll
      for (int r = 0; r < 4; ++r) {
        const int row = bm * 256 + wr * 128 + m * 16 + kb * 4 + r;
        const int col = bn * 256 + wc * 64 + n * 16 + fr;
        const float v = acc[m][n][r];
        const int h = col / DHD, d = col - h * DHD;
        if (mode == 0) {
          const int b = row >> 11, s = row & 2047;
          Qa[(((size_t)(b * NH + h)) * NS + s) * DHP + d] =
              __float2half(v * 0.11180339887498949f);     // 1/sqrt(80) folded
        } else if (mode == 1) {
          const int b = row >> 9, l = row & 511;
          Ka[(((size_t)(b * NH + h)) * NL + l) * DHP + d] = __float2half(v);
        } else {
          const int b = row >> 9, l = row & 511;
          Va[(((size_t)(b * NH + h)) * DHP + d) * NL + l] = __float2half(v);
        }
      }
}

// -------- O projection: out = gate * (AO x Wo^T), fp32, 160 blocks -------
__global__ __launch_bounds__(512) void gemm256_o(const __half* __restrict__ A,
                                                 const __half* __restrict__ Bt,
                                                 float* __restrict__ out,
                                                 const float* __restrict__ gate_p) {
  __shared__ __half smem[2 * 32768];
  int wg = blockIdx.x;                       // 160 = 8 XCD * 20
  wg = (wg & 7) * 20 + (wg >> 3);
  const int bm = wg / 10, bn = wg - bm * 10;

  f32x4_t acc[8][4] = {};
  gemm256_core(A, Bt, bm, bn, smem, acc);

  const float gate = tanhf(gate_p[0]);
  const int lane = threadIdx.x & 63, wave = threadIdx.x >> 6;
  const int wr = wave >> 2, wc = wave & 3;
  const int fr = lane & 15, kb = lane >> 4;

#pragma unroll
  for (int m = 0; m < 8; ++m)
#pragma unroll
    for (int n = 0; n < 4; ++n)
#pragma unroll
      for (int r = 0; r < 4; ++r) {
        const int row = bm * 256 + wr * 128 + m * 16 + kb * 4 + r;
        const int col = bn * 256 + wc * 64 + n * 16 + fr;
        out[(size_t)row * HID + col] = gate * acc[m][n][r];
      }
}

// ------- attention: K/V staged per-block in LDS (64-key chunks) ----------
// grid (NS/64, NB*NH); 4 waves x 16 Q-rows. Scores in registers.
// LDS: Pl 65KB (per-wave P fp16) + 12KB shared K/V chunk = 78.8KB -> 2 blk/CU.
__global__ __launch_bounds__(256) void attn_kernel(const __half* __restrict__ Q,
                                                   const __half* __restrict__ Kt,
                                                   const __half* __restrict__ Vt,
                                                   float* __restrict__ P,
                                                   __half* __restrict__ AO) {
  __shared__ __half Pl[4 * 16 * 520];
  __shared__ __half KV[6144];          // K chunk: 64x96 | V chunk: 80 rows x 72-half stride
  const int tid = threadIdx.x;
  const int lane = tid & 63, wave = tid >> 6;
  const int fr = lane & 15, kb = lane >> 4;
  const int bh = blockIdx.y;
  const int r0 = blockIdx.x * 64 + wave * 16;

  const __half* Qb = Q  + ((size_t)bh * NS + r0) * DHP;
  const __half* Kb = Kt + (size_t)bh * NL * DHP;
  const __half* Vb = Vt + (size_t)bh * DHP * NL;

  half8_t aq[3];
#pragma unroll
  for (int kk = 0; kk < 3; ++kk)
    aq[kk] = *(const half8_t*)(Qb + (size_t)fr * DHP + kk * 32 + kb * 8);

  f32x4_t scr[32];

  // ---- QK^T in 8 chunks of 64 keys staged in LDS (shared by 4 waves) ----
  for (int c = 0; c < 8; ++c) {
    // stage 64 rows x 96 halfs = 768 x 16B slots, linear (bank-uniform reads)
#pragma unroll
    for (int i = 0; i < 3; ++i) {
      const int s = (wave * 3 + i) * 64 + lane;
      gload_lds16(Kb + (size_t)c * 64 * DHP + s * 8, KV + s * 8);
    }
    __syncthreads();   // waitcnt 0 + barrier: chunk fully landed
#pragma unroll
    for (int ntl = 0; ntl < 4; ++ntl) {
      f32x4_t a = {};
#pragma unroll
      for (int kk = 0; kk < 3; ++kk) {
        half8_t bfv = *(const half8_t*)(KV + (ntl * 16 + fr) * DHP + kk * 32 + kb * 8);
        a = __builtin_amdgcn_mfma_f32_16x16x32_f16(aq[kk], bfv, a, 0, 0, 0);
      }
      scr[c * 4 + ntl] = a;
    }
    __syncthreads();   // all waves done reading before next-chunk overwrite
  }

  // ---- softmax (exact): lane holds rows kb*4+r, col nt*16+fr ----
  __half* Plw = Pl + wave * (16 * 520);
#pragma unroll
  for (int r = 0; r < 4; ++r) {
    float m = -1e30f;
#pragma unroll
    for (int nt = 0; nt < 32; ++nt) m = fmaxf(m, scr[nt][r]);
#pragma unroll
    for (int d = 1; d < 16; d <<= 1) m = fmaxf(m, __shfl_xor(m, d));
    float s = 0.f;
#pragma unroll
    for (int nt = 0; nt < 32; ++nt) {
      float p = __expf(scr[nt][r] - m);
      scr[nt][r] = p;
      s += p;
    }
#pragma unroll
    for (int d = 1; d < 16; d <<= 1) s += __shfl_xor(s, d);
    const float iv = 1.f / s;
    const int srow = r0 + kb * 4 + r;
    float* Pr = P + ((size_t)bh * NS + srow) * NL;
#pragma unroll
    for (int nt = 0; nt < 32; ++nt) {
      float p = scr[nt][r] * iv;
      Pr[nt * 16 + fr] = p;
      Plw[(kb * 4 + r) * 520 + nt * 16 + fr] = __float2half(p);
    }
  }

  // ---- PV in 8 chunks of 64 keys; V chunk staged at 72-half row stride ----
  f32x4_t oc[5] = {};
  for (int c = 0; c < 8; ++c) {
#pragma unroll
    for (int i = 0; i < 3; ++i) {
      const int s = (wave * 3 + i) * 64 + lane;   // 0..767 (720 valid)
      int row = s / 9;
      int col = s - row * 9;
      if (row > 79) row = 79;
      if (col > 7) col = 7;
      gload_lds16(Vb + (size_t)row * NL + c * 64 + col * 8, KV + s * 8);
    }
    __syncthreads();
#pragma unroll
    for (int k0l = 0; k0l < 2; ++k0l) {
      half8_t ap = *(const half8_t*)(Plw + fr * 520 + (c * 2 + k0l) * 32 + kb * 8);
#pragma unroll
      for (int n = 0; n < 5; ++n) {
        half8_t bv = *(const half8_t*)(KV + (n * 16 + fr) * 72 + k0l * 32 + kb * 8);
        oc[n] = __builtin_amdgcn_mfma_f32_16x16x32_f16(ap, bv, oc[n], 0, 0, 0);
      }
    }
    __syncthreads();
  }

  const int b = bh >> 5, h = bh & 31;
#pragma unroll
  for (int n = 0; n < 5; ++n)
#pragma unroll
    for (int r = 0; r < 4; ++r) {
      const int srow = r0 + kb * 4 + r;
      AO[((size_t)b * NS + srow) * HID + h * DHD + n * 16 + fr] = __float2half(oc[n][r]);
    }
}

extern "C" void kernel_launch(void* const* d_in, const int* in_sizes, int n_in,
                              void* d_out, int out_size, void* d_ws, size_t ws_size,
                              hipStream_t stream) {
  const float* X  = (const float*)d_in[0];
  const float* LS = (const float*)d_in[1];
  const float* Wq = (const float*)d_in[2];
  const float* Wk = (const float*)d_in[3];
  const float* Wv = (const float*)d_in[4];
  const float* Wo = (const float*)d_in[5];
  const float* gp = (const float*)d_in[6];
  float* out  = (float*)d_out;
  float* Pout = out + (size_t)NB * NS * HID;

  char* w = (char*)d_ws;
  auto alloc = [&](size_t bytes) {
    char* p = w;
    w += (bytes + 255) & ~(size_t)255;
    return p;
  };
  __half* Xh  = (__half*)alloc((size_t)NB * NS * HID * 2);
  __half* Lh  = (__half*)alloc((size_t)NB * NL * HID * 2);
  __half* Wqh = (__half*)alloc((size_t)HID * HID * 2);
  __half* Wkh = (__half*)alloc((size_t)HID * HID * 2);
  __half* Wvh = (__half*)alloc((size_t)HID * HID * 2);
  __half* Woh = (__half*)alloc((size_t)HID * HID * 2);
  __half* Qa  = (__half*)alloc((size_t)NB * NH * NS * DHP * 2);
  __half* Ka  = (__half*)alloc((size_t)NB * NH * NL * DHP * 2);
  __half* Va  = (__half*)alloc((size_t)NB * NH * DHP * NL * 2);
  (void)alloc(4096);                     // guard region after Va
  __half* AOh = Xh;  // Xh dead after QKV projection

  cast_all<<<dim3(2048), dim3(256), 0, stream>>>(X, LS, Wq, Wk, Wv, Wo,
                                                 Xh, Lh, Wqh, Wkh, Wvh, Woh);
  {
    const int rows = NB * NH * NS + NB * NH * NL;
    zero_pads<<<dim3((rows + 255) / 256), dim3(256), 0, stream>>>(Qa, Ka);
  }

  fused_qkv<<<dim3(240), dim3(512), 0, stream>>>(Xh, Lh, Wqh, Wkh, Wvh, Qa, Ka, Va);
  attn_kernel<<<dim3(NS / 64, NB * NH), dim3(256), 0, stream>>>(
      Qa, Ka, Va, Pout, AOh);
  gemm256_o<<<dim3(160), dim3(512), 0, stream>>>(AOh, Woh, out, gp);
}

// Round 6
// 325.268 us; speedup vs baseline: 1.5724x; 1.0232x over previous
//
#include <hip/hip_runtime.h>
#include <hip/hip_fp16.h>
#include <cstdint>
#include <cstddef>

#define HID 2560
#define NH  32
#define DHD 80
#define DHP 96
#define NB  2
#define NS  2048
#define NL  512

typedef _Float16 half8_t __attribute__((ext_vector_type(8)));
typedef float f32x4_t __attribute__((ext_vector_type(4)));

__device__ __forceinline__ void gload_lds16(const __half* g, __half* l) {
  __builtin_amdgcn_global_load_lds(
      (const __attribute__((address_space(1))) unsigned int*)g,
      (__attribute__((address_space(3))) unsigned int*)l, 16, 0, 0);
}

// ---- fused: cast fp32->fp16 (6 tensors) + zero Q/K pad columns ----------
__global__ __launch_bounds__(256) void cast_all(const float* __restrict__ X,
                                                const float* __restrict__ LS,
                                                const float* __restrict__ Wq,
                                                const float* __restrict__ Wk,
                                                const float* __restrict__ Wv,
                                                const float* __restrict__ Wo,
                                                __half* __restrict__ Xh,
                                                __half* __restrict__ Lh,
                                                __half* __restrict__ Wqh,
                                                __half* __restrict__ Wkh,
                                                __half* __restrict__ Wvh,
                                                __half* __restrict__ Woh,
                                                __half* __restrict__ Qa,
                                                __half* __restrict__ Ka) {
  const int nX = NB * NS * HID / 4, nL = NB * NL * HID / 4, nW = HID * HID / 4;
  const int ncast = nX + nL + 4 * nW;
  const int qrows = NB * NH * NS, krows = NB * NH * NL;
  const int total = ncast + qrows + krows;
  for (int i = blockIdx.x * 256 + threadIdx.x; i < total; i += gridDim.x * 256) {
    if (i < ncast) {
      const float* src; __half* dst; int off;
      if (i < nX) { src = X; dst = Xh; off = i; }
      else if (i < nX + nL) { src = LS; dst = Lh; off = i - nX; }
      else {
        int j = i - nX - nL;
        int w = j / nW; off = j - w * nW;
        src = (w == 0) ? Wq : (w == 1) ? Wk : (w == 2) ? Wv : Wo;
        dst = (w == 0) ? Wqh : (w == 1) ? Wkh : (w == 2) ? Wvh : Woh;
      }
      float4 v = ((const float4*)src)[off];
      union { __half h[4]; uint2 u; } r;
      r.h[0] = __float2half(v.x);
      r.h[1] = __float2half(v.y);
      r.h[2] = __float2half(v.z);
      r.h[3] = __float2half(v.w);
      ((uint2*)dst)[off] = r.u;
    } else {
      // zero the DHP pad columns (d=80..95) of Q / K
      const int j = i - ncast;
      const uint4 z = {0, 0, 0, 0};
      uint4* p = (j < qrows)
          ? (uint4*)(Qa + (size_t)j * DHP + DHD)
          : (uint4*)(Ka + (size_t)(j - qrows) * DHP + DHD);
      p[0] = z; p[1] = z;
    }
  }
}

// ============ 256x256-tile, BK=64, 8-wave core (T2+T3+T4+T5) =============
// Staging front-loaded: phase0 issues half-tiles 0+1 of kt+1, phase1 issues 2,
// phase2 issues 3, phase3 none -> last-issued half-tile gets >=2 phases of
// latency cover; vmcnt(4) leaves the 4 next-tile loads in flight.
__device__ __forceinline__ void gemm256_core(const __half* A, const __half* Bt,
                                             int bm, int bn, __half* smem,
                                             f32x4_t (&acc)[8][4]) {
  const int K = HID;
  const int tid  = threadIdx.x;
  const int lane = tid & 63;
  const int wave = tid >> 6;
  const int wr = wave >> 2, wc = wave & 3;
  const int fr = lane & 15, kb = lane >> 4;

  const int sr = tid >> 3;
  const int sj = (tid & 7) ^ (sr & 7);
  const __half* gA = A  + (size_t)(bm * 256 + sr) * K + sj * 8;
  const __half* gB = Bt + (size_t)(bn * 256 + sr) * K + sj * 8;

  auto stage = [&](int h, int kt, int bank) {
    const __half* gbase = (h < 2) ? gA : gB;
    const int rbase = (h & 1) * 128;
#pragma unroll
    for (int i = 0; i < 2; ++i) {
      const __half* g = gbase + (size_t)(rbase + i * 64) * K + (size_t)kt * 64;
      __half* l = smem + bank * 32768 + (h < 2 ? 0 : 16384) + (rbase + i * 64) * 64 + tid * 8;
      gload_lds16(g, l);
    }
  };
  auto rdA = [&](int m, int kk, int bank) -> half8_t {
    const int row = wr * 128 + m * 16 + fr;
    const int off = row * 128 + ((kk * 64 + kb * 16) ^ ((fr & 7) << 4));
    return *(const half8_t*)((const char*)(smem + bank * 32768) + off);
  };
  auto rdB = [&](int n, int kk, int bank) -> half8_t {
    const int row = wc * 64 + n * 16 + fr;
    const int off = row * 128 + ((kk * 64 + kb * 16) ^ ((fr & 7) << 4));
    return *(const half8_t*)((const char*)(smem + bank * 32768 + 16384) + off);
  };

  half8_t af[4][2], bf[4][2];

#pragma unroll
  for (int h = 0; h < 4; ++h) stage(h, 0, 0);

  const int nk = K >> 6;
  for (int kt = 0; kt < nk; ++kt) {
    const int bk = kt & 1, nb2 = bk ^ 1;
    const bool pf = (kt + 1 < nk);

    // ---- phase 0: (m0-3, n0-1); issue half-tiles 0+1 of kt+1
    if (pf) { stage(0, kt + 1, nb2); stage(1, kt + 1, nb2); }
    if (pf) asm volatile("s_waitcnt vmcnt(4)" ::: "memory");
    else    asm volatile("s_waitcnt vmcnt(0)" ::: "memory");
    asm volatile("s_barrier" ::: "memory");
#pragma unroll
    for (int m = 0; m < 4; ++m)
#pragma unroll
      for (int kk = 0; kk < 2; ++kk) af[m][kk] = rdA(m, kk, bk);
#pragma unroll
    for (int n = 0; n < 2; ++n)
#pragma unroll
      for (int kk = 0; kk < 2; ++kk) bf[n][kk] = rdB(n, kk, bk);
    __builtin_amdgcn_s_setprio(1);
#pragma unroll
    for (int m = 0; m < 4; ++m)
#pragma unroll
      for (int n = 0; n < 2; ++n)
#pragma unroll
        for (int kk = 0; kk < 2; ++kk)
          acc[m][n] = __builtin_amdgcn_mfma_f32_16x16x32_f16(af[m][kk], bf[n][kk], acc[m][n], 0, 0, 0);
    __builtin_amdgcn_s_setprio(0);
    asm volatile("s_barrier" ::: "memory");

    // ---- phase 1: (m0-3, n2-3); issue half-tile 2
#pragma unroll
    for (int n = 2; n < 4; ++n)
#pragma unroll
      for (int kk = 0; kk < 2; ++kk) bf[n][kk] = rdB(n, kk, bk);
    if (pf) stage(2, kt + 1, nb2);
    asm volatile("s_barrier" ::: "memory");
    __builtin_amdgcn_s_setprio(1);
#pragma unroll
    for (int m = 0; m < 4; ++m)
#pragma unroll
      for (int n = 2; n < 4; ++n)
#pragma unroll
        for (int kk = 0; kk < 2; ++kk)
          acc[m][n] = __builtin_amdgcn_mfma_f32_16x16x32_f16(af[m][kk], bf[n][kk], acc[m][n], 0, 0, 0);
    __builtin_amdgcn_s_setprio(0);
    asm volatile("s_barrier" ::: "memory");

    // ---- phase 2: (m4-7, n2-3); issue half-tile 3
#pragma unroll
    for (int m = 0; m < 4; ++m)
#pragma unroll
      for (int kk = 0; kk < 2; ++kk) af[m][kk] = rdA(m + 4, kk, bk);
    if (pf) stage(3, kt + 1, nb2);
    asm volatile("s_barrier" ::: "memory");
    __builtin_amdgcn_s_setprio(1);
#pragma unroll
    for (int m = 0; m < 4; ++m)
#pragma unroll
      for (int n = 2; n < 4; ++n)
#pragma unroll
        for (int kk = 0; kk < 2; ++kk)
          acc[m + 4][n] = __builtin_amdgcn_mfma_f32_16x16x32_f16(af[m][kk], bf[n][kk], acc[m + 4][n], 0, 0, 0);
    __builtin_amdgcn_s_setprio(0);
    asm volatile("s_barrier" ::: "memory");

    // ---- phase 3: (m4-7, n0-1); no staging
    asm volatile("s_barrier" ::: "memory");
    __builtin_amdgcn_s_setprio(1);
#pragma unroll
    for (int m = 0; m < 4; ++m)
#pragma unroll
      for (int n = 0; n < 2; ++n)
#pragma unroll
        for (int kk = 0; kk < 2; ++kk)
          acc[m + 4][n] = __builtin_amdgcn_mfma_f32_16x16x32_f16(af[m][kk], bf[n][kk], acc[m + 4][n], 0, 0, 0);
    __builtin_amdgcn_s_setprio(0);
    asm volatile("s_barrier" ::: "memory");
  }
}

// -------- fused QKV projection: 240 blocks = 160 Q + 40 K + 40 V ---------
__global__ __launch_bounds__(512) void fused_qkv(const __half* __restrict__ X,
                                                 const __half* __restrict__ L,
                                                 const __half* __restrict__ Wq,
                                                 const __half* __restrict__ Wk,
                                                 const __half* __restrict__ Wv,
                                                 __half* __restrict__ Qa,
                                                 __half* __restrict__ Ka,
                                                 __half* __restrict__ Va) {
  __shared__ __half smem[2 * 32768];
  int wg = blockIdx.x;                       // 240 = 8 XCD * 30
  wg = (wg & 7) * 30 + (wg >> 3);            // bijective XCD swizzle

  int mode, bm, bn;
  const __half *A, *B;
  if (wg < 160)      { mode = 0; A = X; B = Wq; bm = wg / 10;        bn = wg - bm * 10; }
  else if (wg < 200) { mode = 1; A = L; B = Wk; bm = (wg - 160) / 10; bn = (wg - 160) - bm * 10; }
  else               { mode = 2; A = L; B = Wv; bm = (wg - 200) / 10; bn = (wg - 200) - bm * 10; }

  f32x4_t acc[8][4] = {};
  gemm256_core(A, B, bm, bn, smem, acc);

  const int lane = threadIdx.x & 63, wave = threadIdx.x >> 6;
  const int wr = wave >> 2, wc = wave & 3;
  const int fr = lane & 15, kb = lane >> 4;

#pragma unroll
  for (int m = 0; m < 8; ++m)
#pragma unroll
    for (int n = 0; n < 4; ++n)
#pragma unroll
      for (int r = 0; r < 4; ++r) {
        const int row = bm * 256 + wr * 128 + m * 16 + kb * 4 + r;
        const int col = bn * 256 + wc * 64 + n * 16 + fr;
        const float v = acc[m][n][r];
        const int h = col / DHD, d = col - h * DHD;
        if (mode == 0) {
          const int b = row >> 11, s = row & 2047;
          Qa[(((size_t)(b * NH + h)) * NS + s) * DHP + d] =
              __float2half(v * 0.11180339887498949f);     // 1/sqrt(80) folded
        } else if (mode == 1) {
          const int b = row >> 9, l = row & 511;
          Ka[(((size_t)(b * NH + h)) * NL + l) * DHP + d] = __float2half(v);
        } else {
          const int b = row >> 9, l = row & 511;
          Va[(((size_t)(b * NH + h)) * DHP + d) * NL + l] = __float2half(v);
        }
      }
}

// -------- O projection: out = gate * (AO x Wo^T), fp32, 160 blocks -------
__global__ __launch_bounds__(512) void gemm256_o(const __half* __restrict__ A,
                                                 const __half* __restrict__ Bt,
                                                 float* __restrict__ out,
                                                 const float* __restrict__ gate_p) {
  __shared__ __half smem[2 * 32768];
  int wg = blockIdx.x;                       // 160 = 8 XCD * 20
  wg = (wg & 7) * 20 + (wg >> 3);
  const int bm = wg / 10, bn = wg - bm * 10;

  f32x4_t acc[8][4] = {};
  gemm256_core(A, Bt, bm, bn, smem, acc);

  const float gate = tanhf(gate_p[0]);
  const int lane = threadIdx.x & 63, wave = threadIdx.x >> 6;
  const int wr = wave >> 2, wc = wave & 3;
  const int fr = lane & 15, kb = lane >> 4;

#pragma unroll
  for (int m = 0; m < 8; ++m)
#pragma unroll
    for (int n = 0; n < 4; ++n)
#pragma unroll
      for (int r = 0; r < 4; ++r) {
        const int row = bm * 256 + wr * 128 + m * 16 + kb * 4 + r;
        const int col = bn * 256 + wc * 64 + n * 16 + fr;
        out[(size_t)row * HID + col] = gate * acc[m][n][r];
      }
}

// ------- attention: K/V staged per-block in LDS (64-key chunks) ----------
__global__ __launch_bounds__(256) void attn_kernel(const __half* __restrict__ Q,
                                                   const __half* __restrict__ Kt,
                                                   const __half* __restrict__ Vt,
                                                   float* __restrict__ P,
                                                   __half* __restrict__ AO) {
  __shared__ __half Pl[4 * 16 * 520];
  __shared__ __half KV[6144];
  const int tid = threadIdx.x;
  const int lane = tid & 63, wave = tid >> 6;
  const int fr = lane & 15, kb = lane >> 4;
  const int bh = blockIdx.y;
  const int r0 = blockIdx.x * 64 + wave * 16;

  const __half* Qb = Q  + ((size_t)bh * NS + r0) * DHP;
  const __half* Kb = Kt + (size_t)bh * NL * DHP;
  const __half* Vb = Vt + (size_t)bh * DHP * NL;

  half8_t aq[3];
#pragma unroll
  for (int kk = 0; kk < 3; ++kk)
    aq[kk] = *(const half8_t*)(Qb + (size_t)fr * DHP + kk * 32 + kb * 8);

  f32x4_t scr[32];

  for (int c = 0; c < 8; ++c) {
#pragma unroll
    for (int i = 0; i < 3; ++i) {
      const int s = (wave * 3 + i) * 64 + lane;
      gload_lds16(Kb + (size_t)c * 64 * DHP + s * 8, KV + s * 8);
    }
    __syncthreads();
#pragma unroll
    for (int ntl = 0; ntl < 4; ++ntl) {
      f32x4_t a = {};
#pragma unroll
      for (int kk = 0; kk < 3; ++kk) {
        half8_t bfv = *(const half8_t*)(KV + (ntl * 16 + fr) * DHP + kk * 32 + kb * 8);
        a = __builtin_amdgcn_mfma_f32_16x16x32_f16(aq[kk], bfv, a, 0, 0, 0);
      }
      scr[c * 4 + ntl] = a;
    }
    __syncthreads();
  }

  __half* Plw = Pl + wave * (16 * 520);
#pragma unroll
  for (int r = 0; r < 4; ++r) {
    float m = -1e30f;
#pragma unroll
    for (int nt = 0; nt < 32; ++nt) m = fmaxf(m, scr[nt][r]);
#pragma unroll
    for (int d = 1; d < 16; d <<= 1) m = fmaxf(m, __shfl_xor(m, d));
    float s = 0.f;
#pragma unroll
    for (int nt = 0; nt < 32; ++nt) {
      float p = __expf(scr[nt][r] - m);
      scr[nt][r] = p;
      s += p;
    }
#pragma unroll
    for (int d = 1; d < 16; d <<= 1) s += __shfl_xor(s, d);
    const float iv = 1.f / s;
    const int srow = r0 + kb * 4 + r;
    float* Pr = P + ((size_t)bh * NS + srow) * NL;
#pragma unroll
    for (int nt = 0; nt < 32; ++nt) {
      float p = scr[nt][r] * iv;
      Pr[nt * 16 + fr] = p;
      Plw[(kb * 4 + r) * 520 + nt * 16 + fr] = __float2half(p);
    }
  }

  f32x4_t oc[5] = {};
  for (int c = 0; c < 8; ++c) {
#pragma unroll
    for (int i = 0; i < 3; ++i) {
      const int s = (wave * 3 + i) * 64 + lane;
      int row = s / 9;
      int col = s - row * 9;
      if (row > 79) row = 79;
      if (col > 7) col = 7;
      gload_lds16(Vb + (size_t)row * NL + c * 64 + col * 8, KV + s * 8);
    }
    __syncthreads();
#pragma unroll
    for (int k0l = 0; k0l < 2; ++k0l) {
      half8_t ap = *(const half8_t*)(Plw + fr * 520 + (c * 2 + k0l) * 32 + kb * 8);
#pragma unroll
      for (int n = 0; n < 5; ++n) {
        half8_t bv = *(const half8_t*)(KV + (n * 16 + fr) * 72 + k0l * 32 + kb * 8);
        oc[n] = __builtin_amdgcn_mfma_f32_16x16x32_f16(ap, bv, oc[n], 0, 0, 0);
      }
    }
    __syncthreads();
  }

  const int b = bh >> 5, h = bh & 31;
#pragma unroll
  for (int n = 0; n < 5; ++n)
#pragma unroll
    for (int r = 0; r < 4; ++r) {
      const int srow = r0 + kb * 4 + r;
      AO[((size_t)b * NS + srow) * HID + h * DHD + n * 16 + fr] = __float2half(oc[n][r]);
    }
}

extern "C" void kernel_launch(void* const* d_in, const int* in_sizes, int n_in,
                              void* d_out, int out_size, void* d_ws, size_t ws_size,
                              hipStream_t stream) {
  const float* X  = (const float*)d_in[0];
  const float* LS = (const float*)d_in[1];
  const float* Wq = (const float*)d_in[2];
  const float* Wk = (const float*)d_in[3];
  const float* Wv = (const float*)d_in[4];
  const float* Wo = (const float*)d_in[5];
  const float* gp = (const float*)d_in[6];
  float* out  = (float*)d_out;
  float* Pout = out + (size_t)NB * NS * HID;

  char* w = (char*)d_ws;
  auto alloc = [&](size_t bytes) {
    char* p = w;
    w += (bytes + 255) & ~(size_t)255;
    return p;
  };
  __half* Xh  = (__half*)alloc((size_t)NB * NS * HID * 2);
  __half* Lh  = (__half*)alloc((size_t)NB * NL * HID * 2);
  __half* Wqh = (__half*)alloc((size_t)HID * HID * 2);
  __half* Wkh = (__half*)alloc((size_t)HID * HID * 2);
  __half* Wvh = (__half*)alloc((size_t)HID * HID * 2);
  __half* Woh = (__half*)alloc((size_t)HID * HID * 2);
  __half* Qa  = (__half*)alloc((size_t)NB * NH * NS * DHP * 2);
  __half* Ka  = (__half*)alloc((size_t)NB * NH * NL * DHP * 2);
  __half* Va  = (__half*)alloc((size_t)NB * NH * DHP * NL * 2);
  (void)alloc(4096);                     // guard region after Va
  __half* AOh = Xh;  // Xh dead after QKV projection

  cast_all<<<dim3(2048), dim3(256), 0, stream>>>(X, LS, Wq, Wk, Wv, Wo,
                                                 Xh, Lh, Wqh, Wkh, Wvh, Woh,
                                                 Qa, Ka);
  fused_qkv<<<dim3(240), dim3(512), 0, stream>>>(Xh, Lh, Wqh, Wkh, Wvh, Qa, Ka, Va);
  attn_kernel<<<dim3(NS / 64, NB * NH), dim3(256), 0, stream>>>(
      Qa, Ka, Va, Pout, AOh);
  gemm256_o<<<dim3(160), dim3(512), 0, stream>>>(AOh, Woh, out, gp);
}